// Round 4
// baseline (290.347 us; speedup 1.0000x reference)
//
#include <hip/hip_runtime.h>
#include <hip/hip_bf16.h>
#include <stdint.h>

#define CC 256
#define CQD 32
#define NND 4096

typedef __bf16 bf16x8 __attribute__((ext_vector_type(8)));
typedef float f32x4 __attribute__((ext_vector_type(4)));

__device__ __forceinline__ bf16x8 ld_bf16x8(const __bf16* p) {
    return *reinterpret_cast<const bf16x8*>(p);
}

// ---------------- weight conversion ----------------
__global__ __launch_bounds__(256) void prep_weights(
    const float* __restrict__ wq, const float* __restrict__ wk,
    const float* __restrict__ wv, __bf16* __restrict__ wqkb,
    __bf16* __restrict__ wvb) {
    int i = blockIdx.x * 256 + threadIdx.x;
    if (i < 32 * 256) {
        wqkb[i] = (__bf16)wq[i];
    } else if (i < 64 * 256) {
        wqkb[i] = (__bf16)wk[i - 32 * 256];
    } else {
        int j = i - 64 * 256;
        if (j < 256 * 256) wvb[j] = (__bf16)wv[j];
    }
}

// ---------------- x transpose: [b][C][N] f32 -> [b][N][C] bf16 ----------------
__global__ __launch_bounds__(256) void transpose_x(const float* __restrict__ x,
                                                   __bf16* __restrict__ xbT) {
    __shared__ __bf16 tile[64][65];
    int b = blockIdx.z, c0 = blockIdx.y * 64, n0 = blockIdx.x * 64;
    int tx = threadIdx.x & 63;
    int ty = threadIdx.x >> 6;  // 0..3
    const float* src = x + ((size_t)b * CC + c0) * NND + n0;
#pragma unroll
    for (int i = 0; i < 16; i++) {
        int cc = i * 4 + ty;
        tile[cc][tx] = (__bf16)src[(size_t)cc * NND + tx];
    }
    __syncthreads();
    __bf16* dst = xbT + ((size_t)b * NND + n0) * CC + c0;
#pragma unroll
    for (int i = 0; i < 16; i++) {
        int nn = i * 4 + ty;
        dst[(size_t)nn * CC + tx] = tile[tx][nn];
    }
}

// ---------------- fused q/k/v projection ----------------
// q[b][N][32], k[b][N][32], v[b][C][N]; one pass over xbT.
__global__ __launch_bounds__(256, 2) void proj_qkv(
    const __bf16* __restrict__ xbT, const __bf16* __restrict__ wqkb,
    const __bf16* __restrict__ wvb, const float* __restrict__ bq,
    const float* __restrict__ bk, const float* __restrict__ bv,
    __bf16* __restrict__ qb, __bf16* __restrict__ kb,
    __bf16* __restrict__ vb) {
    const int b = blockIdx.y;
    const int n0 = blockIdx.x * 64;
    const int lane = threadIdx.x & 63;
    const int w = threadIdx.x >> 6;
    const int l15 = lane & 15;
    const int quad = lane >> 4;
    const int n = n0 + w * 16 + l15;
    const __bf16* xrow = xbT + ((size_t)b * NND + n) * CC + quad * 8;
    const f32x4 fzero = {0.f, 0.f, 0.f, 0.f};
    f32x4 aqk[4];   // mt 0,1 = q(ob 0,16); mt 2,3 = k(ob 0,16)
    f32x4 av[16];   // v c-tiles
#pragma unroll
    for (int i = 0; i < 4; i++) aqk[i] = fzero;
#pragma unroll
    for (int i = 0; i < 16; i++) av[i] = fzero;
#pragma unroll
    for (int k0 = 0; k0 < CC; k0 += 32) {
        bf16x8 bf = ld_bf16x8(xrow + k0);
#pragma unroll
        for (int mt = 0; mt < 4; mt++) {
            bf16x8 af = ld_bf16x8(wqkb + (size_t)(mt * 16 + l15) * CC + k0 + quad * 8);
            aqk[mt] = __builtin_amdgcn_mfma_f32_16x16x32_bf16(af, bf, aqk[mt], 0, 0, 0);
        }
#pragma unroll
        for (int mt = 0; mt < 16; mt++) {
            bf16x8 af = ld_bf16x8(wvb + (size_t)(mt * 16 + l15) * CC + k0 + quad * 8);
            av[mt] = __builtin_amdgcn_mfma_f32_16x16x32_bf16(af, bf, av[mt], 0, 0, 0);
        }
    }
#pragma unroll
    for (int mt = 0; mt < 4; mt++) {
        const int ob = (mt & 1) * 16 + quad * 4;
        const float* bias = (mt < 2) ? bq : bk;
        __bf16* dst = ((mt < 2) ? qb : kb) + ((size_t)b * NND + n) * CQD + ob;
        union { ushort4 u; __bf16 h[4]; } pk;
#pragma unroll
        for (int r = 0; r < 4; r++) pk.h[r] = (__bf16)(aqk[mt][r] + bias[ob + r]);
        *reinterpret_cast<ushort4*>(dst) = pk.u;
    }
#pragma unroll
    for (int mt = 0; mt < 16; mt++) {
#pragma unroll
        for (int r = 0; r < 4; r++) {
            int c = mt * 16 + quad * 4 + r;
            vb[((size_t)b * CC + c) * NND + n] = (__bf16)(av[mt][r] + bv[c]);
        }
    }
}

// ---------------- fused flash attention + epilogue ----------------
// TI=64 i/block, 4 waves, 2 blocks/CU. S^T formulation (A=K, B=Q), per-lane
// softmax rows. PV c-split: wave w owns c in [w*64, w*64+64), all 4 i-tiles.
// V is NEVER staged in LDS: the PV A-fragment V[c][j+quad*8..+7] is 16
// contiguous bytes of vb's native [C][N] layout -> direct global b128 loads
// (L2-resident), prefetched one j-step ahead into registers. Only P/alpha go
// through LDS; Pt/aL are double-buffered -> ONE barrier per j-step.
__global__ __launch_bounds__(256, 2) void attention(
    const __bf16* __restrict__ qb, const __bf16* __restrict__ kb,
    const __bf16* __restrict__ vb, const float* __restrict__ gamma,
    const float* __restrict__ x, float* __restrict__ out) {
    __shared__ __align__(16) __bf16 Pt[2][64 * 72];  // 2 x 9216 B
    __shared__ float aL[2][64];
    __shared__ float lL[64];

    const int b = blockIdx.y;
    const int i0 = blockIdx.x * 64;
    const int tid = threadIdx.x;
    const int w = tid >> 6;
    const int lane = tid & 63;
    const int l15 = lane & 15;
    const int quad = lane >> 4;
    const f32x4 fzero = {0.f, 0.f, 0.f, 0.f};

    // Q fragment (B-operand): n=i = i0 + w*16 + l15, k(c) = quad*8..
    const bf16x8 qf = ld_bf16x8(qb + ((size_t)b * NND + i0 + w * 16 + l15) * CQD + quad * 8);

    const __bf16* kbase = kb + (size_t)b * NND * CQD + l15 * CQD + quad * 8;
    const __bf16* vbase = vb + ((size_t)(b * CC + w * 64 + l15)) * NND + quad * 8;

    f32x4 acc[4][4];  // [ct][it]: c = w*64+ct*16+quad*4+r, i = it*16+l15
#pragma unroll
    for (int ct = 0; ct < 4; ct++)
#pragma unroll
        for (int it = 0; it < 4; it++) acc[ct][it] = fzero;
    float m_i = -1e30f;
    float l_i = 0.f;

    // ---- prologue: K(0), V(0), S(0), softmax(0) -> Pt[0], aL[0] ----
    bf16x8 kf[4];
#pragma unroll
    for (int jt = 0; jt < 4; jt++)
        kf[jt] = ld_bf16x8(kbase + (size_t)jt * 16 * CQD);
    bf16x8 vf[8];  // [ks*4+ct]
#pragma unroll
    for (int ks = 0; ks < 2; ks++)
#pragma unroll
        for (int ct = 0; ct < 4; ct++)
            vf[ks * 4 + ct] = ld_bf16x8(vbase + (size_t)ct * 16 * NND + ks * 32);

    {
        f32x4 sT[4];
#pragma unroll
        for (int jt = 0; jt < 4; jt++)
            sT[jt] = __builtin_amdgcn_mfma_f32_16x16x32_bf16(kf[jt], qf, fzero, 0, 0, 0);
        // load kf for j=64 (used in iter 0's A-phase)
#pragma unroll
        for (int jt = 0; jt < 4; jt++)
            kf[jt] = ld_bf16x8(kbase + (size_t)(64 + jt * 16) * CQD);
        float mx = -1e30f;
#pragma unroll
        for (int jt = 0; jt < 4; jt++)
#pragma unroll
            for (int r = 0; r < 4; r++) mx = fmaxf(mx, sT[jt][r]);
        mx = fmaxf(mx, __shfl_xor(mx, 16));
        mx = fmaxf(mx, __shfl_xor(mx, 32));
        m_i = mx;
        float ps = 0.f;
#pragma unroll
        for (int jt = 0; jt < 4; jt++) {
            union { ushort4 u4; __bf16 h[4]; } pk;
#pragma unroll
            for (int r = 0; r < 4; r++) {
                float p = __expf(sT[jt][r] - mx);
                ps += p;
                pk.h[r] = (__bf16)p;
            }
            *reinterpret_cast<ushort4*>(&Pt[0][(w * 16 + l15) * 72 + jt * 16 + quad * 4]) = pk.u4;
        }
        ps += __shfl_xor(ps, 16);
        ps += __shfl_xor(ps, 32);
        l_i = ps;
        if (quad == 0) aL[0][w * 16 + l15] = 1.0f;  // alpha(0): acc is zero anyway
    }
    __syncthreads();

    // ---- main loop: one barrier per step ----
    for (int j0 = 0; j0 < NND; j0 += 64) {
        const int pb = (j0 >> 6) & 1;
        // A-phase: S/softmax for step j0+64 -> Pt[pb^1], aL[pb^1]
        if (j0 + 64 < NND) {
            f32x4 sT[4];
#pragma unroll
            for (int jt = 0; jt < 4; jt++)
                sT[jt] = __builtin_amdgcn_mfma_f32_16x16x32_bf16(kf[jt], qf, fzero, 0, 0, 0);
            if (j0 + 128 < NND) {
#pragma unroll
                for (int jt = 0; jt < 4; jt++)
                    kf[jt] = ld_bf16x8(kbase + (size_t)(j0 + 128 + jt * 16) * CQD);
            }
            float mx = -1e30f;
#pragma unroll
            for (int jt = 0; jt < 4; jt++)
#pragma unroll
                for (int r = 0; r < 4; r++) mx = fmaxf(mx, sT[jt][r]);
            mx = fmaxf(mx, __shfl_xor(mx, 16));
            mx = fmaxf(mx, __shfl_xor(mx, 32));
            float mnew = fmaxf(m_i, mx);
            float alpha = __expf(m_i - mnew);
            m_i = mnew;
            float ps = 0.f;
#pragma unroll
            for (int jt = 0; jt < 4; jt++) {
                union { ushort4 u4; __bf16 h[4]; } pk;
#pragma unroll
                for (int r = 0; r < 4; r++) {
                    float p = __expf(sT[jt][r] - mnew);
                    ps += p;
                    pk.h[r] = (__bf16)p;
                }
                *reinterpret_cast<ushort4*>(
                    &Pt[pb ^ 1][(w * 16 + l15) * 72 + jt * 16 + quad * 4]) = pk.u4;
            }
            ps += __shfl_xor(ps, 16);
            ps += __shfl_xor(ps, 32);
            l_i = l_i * alpha + ps;
            if (quad == 0) aL[pb ^ 1][w * 16 + l15] = alpha;
        }
        // issue V prefetch for step j0+64 (consumed next iter)
        bf16x8 vnxt[8];
        if (j0 + 64 < NND) {
#pragma unroll
            for (int ks = 0; ks < 2; ks++)
#pragma unroll
                for (int ct = 0; ct < 4; ct++)
                    vnxt[ks * 4 + ct] =
                        ld_bf16x8(vbase + (size_t)ct * 16 * NND + j0 + 64 + ks * 32);
        }
        // B-phase: PV(j0) using vf regs + Pt[pb]
        float avs[4];
#pragma unroll
        for (int it = 0; it < 4; it++) avs[it] = aL[pb][it * 16 + l15];
#pragma unroll
        for (int ct = 0; ct < 4; ct++)
#pragma unroll
            for (int it = 0; it < 4; it++) acc[ct][it] *= avs[it];
#pragma unroll
        for (int ks = 0; ks < 2; ks++) {
#pragma unroll
            for (int it = 0; it < 4; it++) {
                bf16x8 pf = ld_bf16x8(&Pt[pb][(it * 16 + l15) * 72 + ks * 32 + quad * 8]);
#pragma unroll
                for (int ct = 0; ct < 4; ct++)
                    acc[ct][it] = __builtin_amdgcn_mfma_f32_16x16x32_bf16(
                        vf[ks * 4 + ct], pf, acc[ct][it], 0, 0, 0);
            }
        }
        if (j0 + 64 < NND) {
#pragma unroll
            for (int t = 0; t < 8; t++) vf[t] = vnxt[t];
        }
        __syncthreads();
    }

    // epilogue: out = gamma * O / l + x
    if (quad == 0) lL[w * 16 + l15] = l_i;
    __syncthreads();
    float linv[4];
#pragma unroll
    for (int it = 0; it < 4; it++) linv[it] = 1.0f / lL[it * 16 + l15];
    float g = gamma[0];
#pragma unroll
    for (int ct = 0; ct < 4; ct++) {
#pragma unroll
        for (int it = 0; it < 4; it++) {
#pragma unroll
            for (int r = 0; r < 4; r++) {
                int c = w * 64 + ct * 16 + quad * 4 + r;
                int i = i0 + it * 16 + l15;
                size_t off = ((size_t)b * CC + c) * NND + i;
                out[off] = g * (acc[ct][it][r] * linv[it]) + x[off];
            }
        }
    }
}

extern "C" void kernel_launch(void* const* d_in, const int* in_sizes, int n_in,
                              void* d_out, int out_size, void* d_ws, size_t ws_size,
                              hipStream_t stream) {
    const float* x = (const float*)d_in[0];
    const float* wq = (const float*)d_in[1];
    const float* bq = (const float*)d_in[2];
    const float* wk = (const float*)d_in[3];
    const float* bk = (const float*)d_in[4];
    const float* wv = (const float*)d_in[5];
    const float* bv = (const float*)d_in[6];
    const float* gamma = (const float*)d_in[7];
    float* out = (float*)d_out;

    char* ws = (char*)d_ws;
    __bf16* xbT = (__bf16*)ws;                      // 8*4096*256*2 = 16777216
    __bf16* qb = (__bf16*)(ws + 16777216);          // 8*4096*32*2  = 2097152
    __bf16* kb = (__bf16*)(ws + 16777216 + 2097152);
    __bf16* vb = (__bf16*)(ws + 16777216 + 2 * 2097152);  // 8*256*4096*2 = 16777216
    __bf16* wqkb = (__bf16*)(ws + 2 * 16777216 + 2 * 2097152);  // 64*256*2 = 32768
    __bf16* wvb = (__bf16*)(ws + 2 * 16777216 + 2 * 2097152 + 32768);  // 256*256*2

    prep_weights<<<320, 256, 0, stream>>>(wq, wk, wv, wqkb, wvb);
    transpose_x<<<dim3(64, 4, 8), 256, 0, stream>>>(x, xbT);
    proj_qkv<<<dim3(64, 8), 256, 0, stream>>>(xbT, wqkb, wvb, bq, bk, bv, qb, kb, vb);
    attention<<<dim3(64, 8), 256, 0, stream>>>(qb, kb, vb, gamma, x, out);
}